// Round 4
// baseline (372.192 us; speedup 1.0000x reference)
//
#include <hip/hip_runtime.h>
#include <hip/hip_bf16.h>
#include <math.h>

#define S_LEN 2048
#define NHEAD 16
#define DHEAD 128

typedef __attribute__((ext_vector_type(8)))  _Float16 f16x8;
typedef __attribute__((ext_vector_type(4)))  _Float16 f16x4;
typedef __attribute__((ext_vector_type(4)))  float    f32x4;

// ---------------------------------------------------------------------------
// Kernel 1: transpose the two SVD weight mats [H][d][e] f32 -> [H][e][d] f16
// ---------------------------------------------------------------------------
__global__ __launch_bounds__(256) void transpose_w_kernel(
    const float* __restrict__ w_qk, const float* __restrict__ w_v,
    _Float16* __restrict__ wqk_t, _Float16* __restrict__ wv_t)
{
    __shared__ float tile[32][33];
    const int mat = blockIdx.z;
    const int h   = blockIdx.y;
    const int t0  = blockIdx.x;
    const int dt  = (t0 >> 2) * 32;
    const int et  = (t0 & 3) * 32;
    const float* src = (mat ? w_v : w_qk) + (size_t)h * DHEAD * DHEAD;
    _Float16*   dst = (mat ? wv_t : wqk_t) + (size_t)h * DHEAD * DHEAD;
    const int tx = threadIdx.x & 31, ty = threadIdx.x >> 5;
#pragma unroll
    for (int k = 0; k < 4; ++k)
        tile[ty + 8 * k][tx] = src[(size_t)(dt + ty + 8 * k) * DHEAD + et + tx];
    __syncthreads();
#pragma unroll
    for (int k = 0; k < 4; ++k)
        dst[(size_t)(et + ty + 8 * k) * DHEAD + dt + tx] = (_Float16)tile[tx][ty + 8 * k];
}

// ---------------------------------------------------------------------------
// Kernel 2: per-head projection via MFMA 16x16x32 f16.
//   Qp[h][s][e] = (X_q[s] @ W_qk) * log2(e)/sqrt(128)   (f16, pre-scaled)
//   Kp[h][s][e] =  X_k[s] @ W_qk                        (f16)
//   Vt[h][e][s] =  X_v[s] @ W_v (transposed)            (f16)
// ---------------------------------------------------------------------------
__global__ __launch_bounds__(256) void proj_kernel(
    const float* __restrict__ q_in, const float* __restrict__ k_in,
    const float* __restrict__ v_in,
    const _Float16* __restrict__ wqk_t, const _Float16* __restrict__ wv_t,
    _Float16* __restrict__ Qp, _Float16* __restrict__ Kp, _Float16* __restrict__ Vt)
{
    const int h   = blockIdx.x >> 5;
    const int rb  = blockIdx.x & 31;
    const int wv  = threadIdx.x >> 6;
    const int lane = threadIdx.x & 63;
    const int r16 = lane & 15;
    const int kg  = lane >> 4;
    const int s_base = rb * 64 + wv * 16;
    const int s_row  = s_base + r16;
    // 1/sqrt(128) * log2(e)  -- softmax runs in exp2 domain
    const float INV_NORM = 0.12752211758f;

    f16x8 aq[4], ak[4], av[4];
    {
        const float* qr = q_in + ((size_t)s_row * NHEAD + h) * DHEAD;
        const float* kr = k_in + ((size_t)s_row * NHEAD + h) * DHEAD;
        const float* vr = v_in + ((size_t)s_row * NHEAD + h) * DHEAD;
#pragma unroll
        for (int kb = 0; kb < 4; ++kb) {
            const int d0 = kb * 32 + kg * 8;
            const f32x4 q0 = *(const f32x4*)(qr + d0), q1 = *(const f32x4*)(qr + d0 + 4);
            const f32x4 k0 = *(const f32x4*)(kr + d0), k1 = *(const f32x4*)(kr + d0 + 4);
            const f32x4 v0 = *(const f32x4*)(vr + d0), v1 = *(const f32x4*)(vr + d0 + 4);
#pragma unroll
            for (int i = 0; i < 4; ++i) {
                aq[kb][i] = (_Float16)q0[i];  aq[kb][i + 4] = (_Float16)q1[i];
                ak[kb][i] = (_Float16)k0[i];  ak[kb][i + 4] = (_Float16)k1[i];
                av[kb][i] = (_Float16)v0[i];  av[kb][i + 4] = (_Float16)v1[i];
            }
        }
    }

    const _Float16* wq_h = wqk_t + (size_t)h * DHEAD * DHEAD;
    const _Float16* wv_h = wv_t  + (size_t)h * DHEAD * DHEAD;

#pragma unroll 2
    for (int cb = 0; cb < 8; ++cb) {
        f32x4 accq = {0.f, 0.f, 0.f, 0.f};
        f32x4 acck = {0.f, 0.f, 0.f, 0.f};
        f32x4 accv = {0.f, 0.f, 0.f, 0.f};
        const int c = cb * 16 + r16;
#pragma unroll
        for (int kb = 0; kb < 4; ++kb) {
            const f16x8 bqk = *(const f16x8*)(wq_h + (size_t)c * DHEAD + kb * 32 + kg * 8);
            const f16x8 bv  = *(const f16x8*)(wv_h + (size_t)c * DHEAD + kb * 32 + kg * 8);
            accq = __builtin_amdgcn_mfma_f32_16x16x32_f16(aq[kb], bqk, accq, 0, 0, 0);
            acck = __builtin_amdgcn_mfma_f32_16x16x32_f16(ak[kb], bqk, acck, 0, 0, 0);
            accv = __builtin_amdgcn_mfma_f32_16x16x32_f16(av[kb], bv,  accv, 0, 0, 0);
        }
#pragma unroll
        for (int j = 0; j < 4; ++j) {
            const int sr = s_base + kg * 4 + j;
            Qp[((size_t)h * S_LEN + sr) * DHEAD + c] = (_Float16)(accq[j] * INV_NORM);
            Kp[((size_t)h * S_LEN + sr) * DHEAD + c] = (_Float16)acck[j];
        }
        f16x4 vvv;
#pragma unroll
        for (int j = 0; j < 4; ++j) vvv[j] = (_Float16)accv[j];
        *(f16x4*)(Vt + ((size_t)h * DHEAD + c) * S_LEN + s_base + kg * 4) = vvv;
    }
}

// ---------------------------------------------------------------------------
// Kernel 3: causal flash attention, 16q x 32kv wave tiles, 16x16x32 MFMA.
// Grid (32, H); block 512 = 8 waves: w = tsel*4 + qsub*2 + role.
//   q-tile t = tsel ? 63-x : x (32 rows), wave owns rows [32t+16*qsub, +16).
//   role r processes kv tiles j = r, r+2, ... < t+1 (2-way KV split).
// SIMD k hosts waves k (light) and k+4 (heavy) -> balanced.
// PV uses a k-slot permutation sigma(kg*8+i) = 4kg+i (i<4), 16+4kg+(i-4):
// P stays ENTIRELY in-lane (4x cvt_pkrtz, no permlane/LDS); V is loaded with
// the same sigma (two f16x4 per eb). Consistent by construction.
// ---------------------------------------------------------------------------
__global__ __launch_bounds__(512, 4) void attn_kernel(
    const _Float16* __restrict__ Qp, const _Float16* __restrict__ Kp,
    const _Float16* __restrict__ Vt, float* __restrict__ out)
{
    __shared__ _Float16 obuf[4][16][136];
    __shared__ float    mlbuf[4][2][16];

    const int h    = blockIdx.y;
    const int w    = threadIdx.x >> 6;
    const int lane = threadIdx.x & 63;
    const int r16  = lane & 15;
    const int kg   = lane >> 4;

    const int tsel = w >> 2;
    const int qsub = (w >> 1) & 1;
    const int role = w & 1;
    const int t    = tsel ? (63 - blockIdx.x) : blockIdx.x;
    const int mg   = tsel * 2 + qsub;
    const int q0w  = t * 32 + qsub * 16;
    const int jmax = t + 1;
    const int q_abs = q0w + r16;

    const _Float16* kbase = Kp + (size_t)h * S_LEN * DHEAD;
    const _Float16* vbase = Vt + (size_t)h * DHEAD * S_LEN;

    // Q B-fragments: lane holds Q[q=r16][32*st + kg*8 + i]
    f16x8 qf[4];
    {
        const _Float16* qp = Qp + ((size_t)h * S_LEN + q_abs) * DHEAD + kg * 8;
#pragma unroll
        for (int st = 0; st < 4; ++st) qf[st] = *(const f16x8*)(qp + st * 32);
    }

    // O^T accumulators: acc[eb][jj] -> e = eb*16 + kg*4 + jj, col q = r16
    f32x4 acc[8];
#pragma unroll
    for (int eb = 0; eb < 8; ++eb) acc[eb] = (f32x4){0.f, 0.f, 0.f, 0.f};
    float m_run = -1e30f, l_run = 0.f;

    const int lkoff = r16 * DHEAD + kg * 8;

    auto loadK = [&](f16x8* kf, int j) {
        const _Float16* kp = kbase + (size_t)(j * 32) * DHEAD + lkoff;
#pragma unroll
        for (int b = 0; b < 2; ++b)
#pragma unroll
            for (int st = 0; st < 4; ++st)
                kf[b * 4 + st] = *(const f16x8*)(kp + b * 16 * DHEAD + st * 32);
    };

    auto tile = [&](const f16x8* kf, int j) {
        const int kv0 = j * 32;
        // S^T = K.Q^T : two kv-16 blocks, K=128 in 4 steps
        f32x4 s0 = {0.f, 0.f, 0.f, 0.f}, s1 = {0.f, 0.f, 0.f, 0.f};
#pragma unroll
        for (int st = 0; st < 4; ++st) {
            s0 = __builtin_amdgcn_mfma_f32_16x16x32_f16(kf[st],     qf[st], s0, 0, 0, 0);
            s1 = __builtin_amdgcn_mfma_f32_16x16x32_f16(kf[4 + st], qf[st], s1, 0, 0, 0);
        }
        // V fragments with sigma-permuted k-slots: lane (r16,kg), slot kg*8+i
        //   i<4: kv = kv0 + 4kg + i ; i>=4: kv = kv0 + 16 + 4kg + (i-4)
        f16x8 vf[8];
#pragma unroll
        for (int eb = 0; eb < 8; ++eb) {
            const _Float16* vp = vbase + (size_t)(eb * 16 + r16) * S_LEN + kv0 + kg * 4;
            union { f16x4 h[2]; f16x8 v; } uu;
            uu.h[0] = *(const f16x4*)(vp);
            uu.h[1] = *(const f16x4*)(vp + 16);
            vf[eb] = uu.v;
        }

        float sv[8];
#pragma unroll
        for (int i = 0; i < 4; ++i) { sv[i] = s0[i]; sv[4 + i] = s1[i]; }

        // causal mask (diagonal tile only); kv = kv0 + (i>>2)*16 + kg*4 + (i&3)
        if (j == t) {
#pragma unroll
            for (int i = 0; i < 8; ++i) {
                const int krel = ((i >> 2) << 4) + kg * 4 + (i & 3);
                if (kv0 + krel > q_abs) sv[i] = -1e30f;
            }
        }

        // online softmax, per q-row = r16 (spread over 4 kg lanes)
        float t0 = fmaxf(sv[0], sv[1]), t1 = fmaxf(sv[2], sv[3]);
        float t2 = fmaxf(sv[4], sv[5]), t3 = fmaxf(sv[6], sv[7]);
        float tm = fmaxf(fmaxf(t0, t1), fmaxf(t2, t3));
        tm = fmaxf(tm, __shfl_xor(tm, 16, 64));
        tm = fmaxf(tm, __shfl_xor(tm, 32, 64));
        if (__any(tm > m_run)) {
            const float mnew = fmaxf(m_run, tm);
            const float corr = exp2f(m_run - mnew);
            l_run *= corr;
#pragma unroll
            for (int eb = 0; eb < 8; ++eb)
#pragma unroll
                for (int jj = 0; jj < 4; ++jj) acc[eb][jj] *= corr;
            m_run = mnew;
        }
#pragma unroll
        for (int i = 0; i < 8; ++i) sv[i] = exp2f(sv[i] - m_run);
        float rs = ((sv[0] + sv[1]) + (sv[2] + sv[3])) + ((sv[4] + sv[5]) + (sv[6] + sv[7]));
        rs += __shfl_xor(rs, 16, 64);
        rs += __shfl_xor(rs, 32, 64);
        l_run += rs;

        // PV B-fragment: entirely in-lane (sigma-permuted k-slots)
        union uf8 { unsigned w[4]; f16x8 v; } pb;
        pb.w[0] = __builtin_bit_cast(unsigned, __builtin_amdgcn_cvt_pkrtz(sv[0], sv[1]));
        pb.w[1] = __builtin_bit_cast(unsigned, __builtin_amdgcn_cvt_pkrtz(sv[2], sv[3]));
        pb.w[2] = __builtin_bit_cast(unsigned, __builtin_amdgcn_cvt_pkrtz(sv[4], sv[5]));
        pb.w[3] = __builtin_bit_cast(unsigned, __builtin_amdgcn_cvt_pkrtz(sv[6], sv[7]));

        // O^T += V^T . P^T  (8 independent MFMAs, K=32)
#pragma unroll
        for (int eb = 0; eb < 8; ++eb)
            acc[eb] = __builtin_amdgcn_mfma_f32_16x16x32_f16(vf[eb], pb.v, acc[eb], 0, 0, 0);
    };

    // main loop: K double-buffer, stride 2 tiles (role parity)
    f16x8 ka[8], kb[8];
    int j = role;
    if (j < jmax) loadK(ka, j);
    while (j < jmax) {
        if (j + 2 < jmax) loadK(kb, j + 2);
        tile(ka, j);
        j += 2;
        if (j >= jmax) break;
        if (j + 2 < jmax) loadK(ka, j + 2);
        tile(kb, j);
        j += 2;
    }

    // KV-split combine: role1 writes partial (m,l,O) to LDS; role0 merges
    if (role) {
        if (kg == 0) { mlbuf[mg][0][r16] = m_run; mlbuf[mg][1][r16] = l_run; }
#pragma unroll
        for (int eb = 0; eb < 8; ++eb) {
            f16x4 ob;
#pragma unroll
            for (int jj = 0; jj < 4; ++jj) ob[jj] = (_Float16)acc[eb][jj];
            *(f16x4*)&obuf[mg][r16][eb * 16 + kg * 4] = ob;
        }
    }
    __syncthreads();
    if (!role) {
        const float mb = mlbuf[mg][0][r16];
        const float lb = mlbuf[mg][1][r16];
        const float ms = fmaxf(m_run, mb);
        const float ca = exp2f(m_run - ms);
        const float cb = exp2f(mb - ms);
        const float rinv = 1.0f / (l_run * ca + lb * cb);
        float* orow = out + (size_t)q_abs * (NHEAD * DHEAD) + h * DHEAD;
#pragma unroll
        for (int eb = 0; eb < 8; ++eb) {
            const f16x4 ob = *(const f16x4*)&obuf[mg][r16][eb * 16 + kg * 4];
            f32x4 vv;
#pragma unroll
            for (int jj = 0; jj < 4; ++jj)
                vv[jj] = (acc[eb][jj] * ca + (float)ob[jj] * cb) * rinv;
            *(f32x4*)(orow + eb * 16 + kg * 4) = vv;
        }
    }
}

// ---------------------------------------------------------------------------
extern "C" void kernel_launch(void* const* d_in, const int* in_sizes, int n_in,
                              void* d_out, int out_size, void* d_ws, size_t ws_size,
                              hipStream_t stream) {
    const float* q_in = (const float*)d_in[0];
    const float* k_in = (const float*)d_in[1];
    const float* v_in = (const float*)d_in[2];
    // d_in[3] = attention_mask (strict causal triu) -- implemented analytically
    const float* w_qk = (const float*)d_in[4];
    const float* w_v  = (const float*)d_in[5];
    float* out = (float*)d_out;

    const size_t mat_elems = (size_t)NHEAD * S_LEN * DHEAD;
    const size_t w_elems   = (size_t)NHEAD * DHEAD * DHEAD;
    _Float16* Qp   = (_Float16*)d_ws;
    _Float16* Kp   = Qp + mat_elems;
    _Float16* Vt   = Kp + mat_elems;
    _Float16* Wqkt = Vt + mat_elems;
    _Float16* Wvt  = Wqkt + w_elems;

    transpose_w_kernel<<<dim3(16, NHEAD, 2), dim3(256), 0, stream>>>(w_qk, w_v, Wqkt, Wvt);
    proj_kernel<<<dim3(NHEAD * 32), dim3(256), 0, stream>>>(q_in, k_in, v_in, Wqkt, Wvt, Qp, Kp, Vt);
    attn_kernel<<<dim3(32, NHEAD), dim3(512), 0, stream>>>(Qp, Kp, Vt, out);
}

// Round 5
// 165.675 us; speedup vs baseline: 2.2465x; 2.2465x over previous
//
#include <hip/hip_runtime.h>
#include <hip/hip_bf16.h>
#include <math.h>

#define S_LEN 2048
#define NHEAD 16
#define DHEAD 128

typedef __attribute__((ext_vector_type(8)))  _Float16 f16x8;
typedef __attribute__((ext_vector_type(4)))  _Float16 f16x4;
typedef __attribute__((ext_vector_type(4)))  float    f32x4;

// ---------------------------------------------------------------------------
// Kernel 1: transpose the two SVD weight mats [H][d][e] f32 -> [H][e][d] f16
// ---------------------------------------------------------------------------
__global__ __launch_bounds__(256) void transpose_w_kernel(
    const float* __restrict__ w_qk, const float* __restrict__ w_v,
    _Float16* __restrict__ wqk_t, _Float16* __restrict__ wv_t)
{
    __shared__ float tile[32][33];
    const int mat = blockIdx.z;
    const int h   = blockIdx.y;
    const int t0  = blockIdx.x;
    const int dt  = (t0 >> 2) * 32;
    const int et  = (t0 & 3) * 32;
    const float* src = (mat ? w_v : w_qk) + (size_t)h * DHEAD * DHEAD;
    _Float16*   dst = (mat ? wv_t : wqk_t) + (size_t)h * DHEAD * DHEAD;
    const int tx = threadIdx.x & 31, ty = threadIdx.x >> 5;
#pragma unroll
    for (int k = 0; k < 4; ++k)
        tile[ty + 8 * k][tx] = src[(size_t)(dt + ty + 8 * k) * DHEAD + et + tx];
    __syncthreads();
#pragma unroll
    for (int k = 0; k < 4; ++k)
        dst[(size_t)(et + ty + 8 * k) * DHEAD + dt + tx] = (_Float16)tile[tx][ty + 8 * k];
}

// ---------------------------------------------------------------------------
// Kernel 2: per-head projection via MFMA 16x16x32 f16.
//   Qp[h][s][e] = (X_q[s] @ W_qk) * log2(e)/sqrt(128)   (f16, pre-scaled)
//   Kp[h][s][e] =  X_k[s] @ W_qk                        (f16)
//   Vp[h][e][*] =  X_v[s] @ W_v, transposed AND sigma-permuted within each
//                  32-row kv block: slot kg*8+i holds kv 4kg+i (i<4) /
//                  16+4kg+(i-4) (i>=4)  -> attn PV B-frag needs no shuffles.
// ---------------------------------------------------------------------------
__global__ __launch_bounds__(256) void proj_kernel(
    const float* __restrict__ q_in, const float* __restrict__ k_in,
    const float* __restrict__ v_in,
    const _Float16* __restrict__ wqk_t, const _Float16* __restrict__ wv_t,
    _Float16* __restrict__ Qp, _Float16* __restrict__ Kp, _Float16* __restrict__ Vp)
{
    const int h   = blockIdx.x >> 5;
    const int rb  = blockIdx.x & 31;
    const int wv  = threadIdx.x >> 6;
    const int lane = threadIdx.x & 63;
    const int r16 = lane & 15;
    const int kg  = lane >> 4;
    const int s_base = rb * 64 + wv * 16;
    const int s_row  = s_base + r16;
    // 1/sqrt(128) * log2(e)  -- softmax runs in exp2 domain
    const float INV_NORM = 0.12752211758f;

    f16x8 aq[4], ak[4], av[4];
    {
        const float* qr = q_in + ((size_t)s_row * NHEAD + h) * DHEAD;
        const float* kr = k_in + ((size_t)s_row * NHEAD + h) * DHEAD;
        const float* vr = v_in + ((size_t)s_row * NHEAD + h) * DHEAD;
#pragma unroll
        for (int kb = 0; kb < 4; ++kb) {
            const int d0 = kb * 32 + kg * 8;
            const f32x4 q0 = *(const f32x4*)(qr + d0), q1 = *(const f32x4*)(qr + d0 + 4);
            const f32x4 k0 = *(const f32x4*)(kr + d0), k1 = *(const f32x4*)(kr + d0 + 4);
            const f32x4 v0 = *(const f32x4*)(vr + d0), v1 = *(const f32x4*)(vr + d0 + 4);
#pragma unroll
            for (int i = 0; i < 4; ++i) {
                aq[kb][i] = (_Float16)q0[i];  aq[kb][i + 4] = (_Float16)q1[i];
                ak[kb][i] = (_Float16)k0[i];  ak[kb][i + 4] = (_Float16)k1[i];
                av[kb][i] = (_Float16)v0[i];  av[kb][i + 4] = (_Float16)v1[i];
            }
        }
    }

    const _Float16* wq_h = wqk_t + (size_t)h * DHEAD * DHEAD;
    const _Float16* wv_h = wv_t  + (size_t)h * DHEAD * DHEAD;

    // sigma-permuted V store offset within the 32-row block
    const int vblk_base = rb * 64 + (wv & 2) * 16;          // 32-aligned block start
    const int vslot     = kg * 8 + (wv & 1) * 4;            // chunk slot in block

#pragma unroll 2
    for (int cb = 0; cb < 8; ++cb) {
        f32x4 accq = {0.f, 0.f, 0.f, 0.f};
        f32x4 acck = {0.f, 0.f, 0.f, 0.f};
        f32x4 accv = {0.f, 0.f, 0.f, 0.f};
        const int c = cb * 16 + r16;
#pragma unroll
        for (int kb = 0; kb < 4; ++kb) {
            const f16x8 bqk = *(const f16x8*)(wq_h + (size_t)c * DHEAD + kb * 32 + kg * 8);
            const f16x8 bv  = *(const f16x8*)(wv_h + (size_t)c * DHEAD + kb * 32 + kg * 8);
            accq = __builtin_amdgcn_mfma_f32_16x16x32_f16(aq[kb], bqk, accq, 0, 0, 0);
            acck = __builtin_amdgcn_mfma_f32_16x16x32_f16(ak[kb], bqk, acck, 0, 0, 0);
            accv = __builtin_amdgcn_mfma_f32_16x16x32_f16(av[kb], bv,  accv, 0, 0, 0);
        }
#pragma unroll
        for (int j = 0; j < 4; ++j) {
            const int sr = s_base + kg * 4 + j;
            Qp[((size_t)h * S_LEN + sr) * DHEAD + c] = (_Float16)(accq[j] * INV_NORM);
            Kp[((size_t)h * S_LEN + sr) * DHEAD + c] = (_Float16)acck[j];
        }
        f16x4 vvv;
#pragma unroll
        for (int j = 0; j < 4; ++j) vvv[j] = (_Float16)accv[j];
        *(f16x4*)(Vp + ((size_t)h * DHEAD + c) * S_LEN + vblk_base + vslot) = vvv;
    }
}

// ---------------------------------------------------------------------------
// Kernel 3: causal flash attention, 16q x 32kv wave tiles, 16x16x32 MFMA.
// Grid (32, H); block 512 = 8 waves: w = tsel*4 + qsub*2 + role.
//   q-tile t = tsel ? 63-x : x (32 rows), wave owns rows [32t+16*qsub, +16).
//   role r processes kv tiles j = r, r+2, ... < t+1 (2-way KV split).
// SIMD k hosts waves k (light) and k+4 (heavy) -> balanced.
// P stays ENTIRELY in-lane (4x cvt_pkrtz); V is stored sigma-permuted so
// its B..A-fragment is one contiguous f16x8. No double-buffer: live set
// kept ~100 VGPR so __launch_bounds__(512,4) holds WITHOUT spilling.
// ---------------------------------------------------------------------------
__global__ __launch_bounds__(512, 4) void attn_kernel(
    const _Float16* __restrict__ Qp, const _Float16* __restrict__ Kp,
    const _Float16* __restrict__ Vp, float* __restrict__ out)
{
    __shared__ _Float16 obuf[4][16][136];
    __shared__ float    mlbuf[4][2][16];

    const int h    = blockIdx.y;
    const int w    = threadIdx.x >> 6;
    const int lane = threadIdx.x & 63;
    const int r16  = lane & 15;
    const int kg   = lane >> 4;

    const int tsel = w >> 2;
    const int qsub = (w >> 1) & 1;
    const int role = w & 1;
    const int t    = tsel ? (63 - blockIdx.x) : blockIdx.x;
    const int mg   = tsel * 2 + qsub;
    const int q0w  = t * 32 + qsub * 16;
    const int jmax = t + 1;
    const int q_abs = q0w + r16;

    const _Float16* kbase = Kp + (size_t)h * S_LEN * DHEAD;
    const _Float16* vbase = Vp + (size_t)h * DHEAD * S_LEN;

    // Q B-fragments: lane holds Q[q=r16][32*st + kg*8 + i]
    f16x8 qf[4];
    {
        const _Float16* qp = Qp + ((size_t)h * S_LEN + q_abs) * DHEAD + kg * 8;
#pragma unroll
        for (int st = 0; st < 4; ++st) qf[st] = *(const f16x8*)(qp + st * 32);
    }

    // O^T accumulators: acc[eb][jj] -> e = eb*16 + kg*4 + jj, col q = r16
    f32x4 acc[8];
#pragma unroll
    for (int eb = 0; eb < 8; ++eb) acc[eb] = (f32x4){0.f, 0.f, 0.f, 0.f};
    float m_run = -1e30f, l_run = 0.f;

    for (int j = role; j < jmax; j += 2) {
        const int kv0 = j * 32;
        const _Float16* kp = kbase + (size_t)(kv0 + r16) * DHEAD + kg * 8;

        // --- S^T = K.Q^T, two kv-16 halves with short K live ranges
        f32x4 s0 = {0.f, 0.f, 0.f, 0.f}, s1 = {0.f, 0.f, 0.f, 0.f};
        {
            const f16x8 k0 = *(const f16x8*)(kp);
            const f16x8 k1 = *(const f16x8*)(kp + 32);
            const f16x8 k2 = *(const f16x8*)(kp + 64);
            const f16x8 k3 = *(const f16x8*)(kp + 96);
            s0 = __builtin_amdgcn_mfma_f32_16x16x32_f16(k0, qf[0], s0, 0, 0, 0);
            s0 = __builtin_amdgcn_mfma_f32_16x16x32_f16(k1, qf[1], s0, 0, 0, 0);
            s0 = __builtin_amdgcn_mfma_f32_16x16x32_f16(k2, qf[2], s0, 0, 0, 0);
            s0 = __builtin_amdgcn_mfma_f32_16x16x32_f16(k3, qf[3], s0, 0, 0, 0);
        }
        {
            const _Float16* kp2 = kp + 16 * DHEAD;
            const f16x8 k0 = *(const f16x8*)(kp2);
            const f16x8 k1 = *(const f16x8*)(kp2 + 32);
            const f16x8 k2 = *(const f16x8*)(kp2 + 64);
            const f16x8 k3 = *(const f16x8*)(kp2 + 96);
            s1 = __builtin_amdgcn_mfma_f32_16x16x32_f16(k0, qf[0], s1, 0, 0, 0);
            s1 = __builtin_amdgcn_mfma_f32_16x16x32_f16(k1, qf[1], s1, 0, 0, 0);
            s1 = __builtin_amdgcn_mfma_f32_16x16x32_f16(k2, qf[2], s1, 0, 0, 0);
            s1 = __builtin_amdgcn_mfma_f32_16x16x32_f16(k3, qf[3], s1, 0, 0, 0);
        }

        float sv[8];
#pragma unroll
        for (int i = 0; i < 4; ++i) { sv[i] = s0[i]; sv[4 + i] = s1[i]; }

        // causal mask (diagonal tile only); kv = kv0 + (i>>2)*16 + kg*4 + (i&3)
        if (j == t) {
#pragma unroll
            for (int i = 0; i < 8; ++i) {
                const int krel = ((i >> 2) << 4) + kg * 4 + (i & 3);
                if (kv0 + krel > q_abs) sv[i] = -1e30f;
            }
        }

        // online softmax, per q-row = r16 (spread over 4 kg lanes)
        float t0 = fmaxf(sv[0], sv[1]), t1 = fmaxf(sv[2], sv[3]);
        float t2 = fmaxf(sv[4], sv[5]), t3 = fmaxf(sv[6], sv[7]);
        float tm = fmaxf(fmaxf(t0, t1), fmaxf(t2, t3));
        tm = fmaxf(tm, __shfl_xor(tm, 16, 64));
        tm = fmaxf(tm, __shfl_xor(tm, 32, 64));
        if (__any(tm > m_run)) {
            const float mnew = fmaxf(m_run, tm);
            const float corr = exp2f(m_run - mnew);
            l_run *= corr;
#pragma unroll
            for (int eb = 0; eb < 8; ++eb)
#pragma unroll
                for (int jj = 0; jj < 4; ++jj) acc[eb][jj] *= corr;
            m_run = mnew;
        }
#pragma unroll
        for (int i = 0; i < 8; ++i) sv[i] = exp2f(sv[i] - m_run);
        float rs = ((sv[0] + sv[1]) + (sv[2] + sv[3])) + ((sv[4] + sv[5]) + (sv[6] + sv[7]));
        rs += __shfl_xor(rs, 16, 64);
        rs += __shfl_xor(rs, 32, 64);
        l_run += rs;

        // PV B-fragment: entirely in-lane (sigma-permuted k-slots)
        union uf8 { unsigned w[4]; f16x8 v; } pb;
        pb.w[0] = __builtin_bit_cast(unsigned, __builtin_amdgcn_cvt_pkrtz(sv[0], sv[1]));
        pb.w[1] = __builtin_bit_cast(unsigned, __builtin_amdgcn_cvt_pkrtz(sv[2], sv[3]));
        pb.w[2] = __builtin_bit_cast(unsigned, __builtin_amdgcn_cvt_pkrtz(sv[4], sv[5]));
        pb.w[3] = __builtin_bit_cast(unsigned, __builtin_amdgcn_cvt_pkrtz(sv[6], sv[7]));

        // O^T += V^T . P^T, two 4-eb halves with short V live ranges
        const _Float16* vp = vbase + (size_t)r16 * S_LEN + kv0 + kg * 8;
        {
            const f16x8 v0 = *(const f16x8*)(vp);
            const f16x8 v1 = *(const f16x8*)(vp + 16 * S_LEN);
            const f16x8 v2 = *(const f16x8*)(vp + 32 * S_LEN);
            const f16x8 v3 = *(const f16x8*)(vp + 48 * S_LEN);
            acc[0] = __builtin_amdgcn_mfma_f32_16x16x32_f16(v0, pb.v, acc[0], 0, 0, 0);
            acc[1] = __builtin_amdgcn_mfma_f32_16x16x32_f16(v1, pb.v, acc[1], 0, 0, 0);
            acc[2] = __builtin_amdgcn_mfma_f32_16x16x32_f16(v2, pb.v, acc[2], 0, 0, 0);
            acc[3] = __builtin_amdgcn_mfma_f32_16x16x32_f16(v3, pb.v, acc[3], 0, 0, 0);
        }
        {
            const _Float16* vp2 = vp + 64 * S_LEN;
            const f16x8 v0 = *(const f16x8*)(vp2);
            const f16x8 v1 = *(const f16x8*)(vp2 + 16 * S_LEN);
            const f16x8 v2 = *(const f16x8*)(vp2 + 32 * S_LEN);
            const f16x8 v3 = *(const f16x8*)(vp2 + 48 * S_LEN);
            acc[4] = __builtin_amdgcn_mfma_f32_16x16x32_f16(v0, pb.v, acc[4], 0, 0, 0);
            acc[5] = __builtin_amdgcn_mfma_f32_16x16x32_f16(v1, pb.v, acc[5], 0, 0, 0);
            acc[6] = __builtin_amdgcn_mfma_f32_16x16x32_f16(v2, pb.v, acc[6], 0, 0, 0);
            acc[7] = __builtin_amdgcn_mfma_f32_16x16x32_f16(v3, pb.v, acc[7], 0, 0, 0);
        }
    }

    // KV-split combine: role1 writes partial (m,l,O) to LDS; role0 merges
    if (role) {
        if (kg == 0) { mlbuf[mg][0][r16] = m_run; mlbuf[mg][1][r16] = l_run; }
#pragma unroll
        for (int eb = 0; eb < 8; ++eb) {
            f16x4 ob;
#pragma unroll
            for (int jj = 0; jj < 4; ++jj) ob[jj] = (_Float16)acc[eb][jj];
            *(f16x4*)&obuf[mg][r16][eb * 16 + kg * 4] = ob;
        }
    }
    __syncthreads();
    if (!role) {
        const float mb = mlbuf[mg][0][r16];
        const float lb = mlbuf[mg][1][r16];
        const float ms = fmaxf(m_run, mb);
        const float ca = exp2f(m_run - ms);
        const float cb = exp2f(mb - ms);
        const float rinv = 1.0f / (l_run * ca + lb * cb);
        float* orow = out + (size_t)q_abs * (NHEAD * DHEAD) + h * DHEAD;
#pragma unroll
        for (int eb = 0; eb < 8; ++eb) {
            const f16x4 ob = *(const f16x4*)&obuf[mg][r16][eb * 16 + kg * 4];
            f32x4 vv;
#pragma unroll
            for (int jj = 0; jj < 4; ++jj)
                vv[jj] = (acc[eb][jj] * ca + (float)ob[jj] * cb) * rinv;
            *(f32x4*)(orow + eb * 16 + kg * 4) = vv;
        }
    }
}

// ---------------------------------------------------------------------------
extern "C" void kernel_launch(void* const* d_in, const int* in_sizes, int n_in,
                              void* d_out, int out_size, void* d_ws, size_t ws_size,
                              hipStream_t stream) {
    const float* q_in = (const float*)d_in[0];
    const float* k_in = (const float*)d_in[1];
    const float* v_in = (const float*)d_in[2];
    // d_in[3] = attention_mask (strict causal triu) -- implemented analytically
    const float* w_qk = (const float*)d_in[4];
    const float* w_v  = (const float*)d_in[5];
    float* out = (float*)d_out;

    const size_t mat_elems = (size_t)NHEAD * S_LEN * DHEAD;
    const size_t w_elems   = (size_t)NHEAD * DHEAD * DHEAD;
    _Float16* Qp   = (_Float16*)d_ws;
    _Float16* Kp   = Qp + mat_elems;
    _Float16* Vp   = Kp + mat_elems;
    _Float16* Wqkt = Vp + mat_elems;
    _Float16* Wvt  = Wqkt + w_elems;

    transpose_w_kernel<<<dim3(16, NHEAD, 2), dim3(256), 0, stream>>>(w_qk, w_v, Wqkt, Wvt);
    proj_kernel<<<dim3(NHEAD * 32), dim3(256), 0, stream>>>(q_in, k_in, v_in, Wqkt, Wvt, Qp, Kp, Vp);
    attn_kernel<<<dim3(32, NHEAD), dim3(512), 0, stream>>>(Qp, Kp, Vp, out);
}